// Round 1
// baseline (2131.019 us; speedup 1.0000x reference)
//
#include <hip/hip_runtime.h>
#include <cstdint>
#include <cstddef>

typedef unsigned short u16;
typedef __attribute__((ext_vector_type(8))) short s8v;   // 8 bf16 in 4 VGPRs
typedef __attribute__((ext_vector_type(4))) float f4v;   // MFMA accumulator

#define D_MODEL 1024
#define D_INNER 2048
#define BT      8192   // B*T
#define TLEN    2048
#define NBATCH  4

struct alignas(8) U16x4 { u16 x, y, z, w; };

__device__ __forceinline__ u16 f2bf(float f) {
  union { float f; unsigned u; } c; c.f = f;
  unsigned r = c.u + 0x7FFFu + ((c.u >> 16) & 1u);   // RNE
  return (u16)(r >> 16);
}
__device__ __forceinline__ float bf2f(u16 b) {
  union { unsigned u; float f; } c; c.u = ((unsigned)b) << 16;
  return c.f;
}

// async global->LDS, 16B per lane; LDS dest must be wave-uniform base (+lane*16 by HW)
__device__ __forceinline__ void glds16(const u16* g, const u16* lds) {
  __builtin_amdgcn_global_load_lds(
      (const __attribute__((address_space(1))) unsigned int*)(uintptr_t)g,
      (__attribute__((address_space(3))) unsigned int*)(unsigned int)(uintptr_t)lds,
      16, 0, 0);
}

// C[m,n] = sum_k A[m,k]*B[n,k]; A: MxK row-major, B: NxK row-major (both bf16).
// 256 thr = 4 waves in 2x2; each wave 64x64 = 4x4 tiles of 16x16x32 MFMA.
// EPI 0: split N=4096 -> Cb=xi bf16 (n<2048), Cb2=silu(z) bf16 (n>=2048)
// EPI 1: Cf = exp(sfac[n]*sigmoid(acc+bias[n]))  (lam, fp32)
// EPI 2: Cb = bf16(acc + bias[n])                (v)
// EPI 3: Cf = acc                                (final out)
template<int EPI>
__global__ __launch_bounds__(256, 2)
void gemm_nt(const u16* __restrict__ A, const u16* __restrict__ B,
             int M, int N, int K,
             float* __restrict__ Cf, u16* __restrict__ Cb, u16* __restrict__ Cb2,
             const float* __restrict__ bias, const float* __restrict__ sfac)
{
  __shared__ u16 lA[128 * 32];
  __shared__ u16 lB[128 * 32];
  const int tid  = threadIdx.x;
  const int wave = tid >> 6, lane = tid & 63;
  const int wm = wave >> 1, wn = wave & 1;
  const int bm0 = blockIdx.y * 128, bn0 = blockIdx.x * 128;

  // staging: each wave stages 32 rows of A and 32 rows of B per K-tile (2 glds each)
  const int srow = lane >> 2;
  const int scol = (lane & 3) * 8;
  const u16* pa0 = A + (size_t)(bm0 + wave * 32 + srow) * K + scol;
  const u16* pa1 = pa0 + (size_t)16 * K;
  const u16* pb0 = B + (size_t)(bn0 + wave * 32 + srow) * K + scol;
  const u16* pb1 = pb0 + (size_t)16 * K;
  u16* la0 = lA + (wave * 32) * 32;
  u16* la1 = la0 + 16 * 32;
  u16* lb0 = lB + (wave * 32) * 32;
  u16* lb1 = lb0 + 16 * 32;

  // fragment read addresses: A[m=lane&15][k=(lane>>4)*8+j]
  const int fr = lane & 15, kq = lane >> 4;
  const u16* fA = lA + (wm * 64 + fr) * 32 + kq * 8;
  const u16* fB = lB + (wn * 64 + fr) * 32 + kq * 8;

  f4v acc[4][4];
  const f4v zf = {0.f, 0.f, 0.f, 0.f};
  for (int i = 0; i < 4; ++i)
    for (int j = 0; j < 4; ++j)
      acc[i][j] = zf;

  for (int k0 = 0; k0 < K; k0 += 32) {
    glds16(pa0 + k0, la0);
    glds16(pa1 + k0, la1);
    glds16(pb0 + k0, lb0);
    glds16(pb1 + k0, lb1);
    __syncthreads();
    s8v af[4], bfv[4];
#pragma unroll
    for (int i = 0; i < 4; ++i) af[i] = *(const s8v*)(fA + i * 16 * 32);
#pragma unroll
    for (int j = 0; j < 4; ++j) bfv[j] = *(const s8v*)(fB + j * 16 * 32);
#pragma unroll
    for (int i = 0; i < 4; ++i)
#pragma unroll
      for (int j = 0; j < 4; ++j)
        acc[i][j] = __builtin_amdgcn_mfma_f32_16x16x32_bf16(af[i], bfv[j], acc[i][j], 0, 0, 0);
    __syncthreads();
  }

  // C/D layout: col = lane&15, row = (lane>>4)*4 + reg
#pragma unroll
  for (int i = 0; i < 4; ++i) {
#pragma unroll
    for (int j = 0; j < 4; ++j) {
#pragma unroll
      for (int r = 0; r < 4; ++r) {
        const int gm = bm0 + wm * 64 + i * 16 + kq * 4 + r;
        const int gn = bn0 + wn * 64 + j * 16 + fr;
        const float val = acc[i][j][r];
        if (EPI == 0) {
          if (gn < D_INNER) {
            Cb[(size_t)gm * D_INNER + gn] = f2bf(val);
          } else {
            const float s = val / (1.f + __expf(-val));  // silu(z)
            Cb2[(size_t)gm * D_INNER + (gn - D_INNER)] = f2bf(s);
          }
        } else if (EPI == 1) {
          const float pre = val + bias[gn];
          const float sig = 1.f / (1.f + __expf(-pre));
          Cf[(size_t)gm * N + gn] = __expf(sfac[gn] * sig);
        } else if (EPI == 2) {
          Cb[(size_t)gm * N + gn] = f2bf(val + bias[gn]);
        } else {
          Cf[(size_t)gm * N + gn] = val;
        }
      }
    }
  }
}

__global__ void conv_bf16_kernel(const float* __restrict__ in, u16* __restrict__ out, int n4)
{
  const int i = blockIdx.x * blockDim.x + threadIdx.x;
  if (i >= n4) return;
  const float4 x = ((const float4*)in)[i];
  U16x4 o; o.x = f2bf(x.x); o.y = f2bf(x.y); o.z = f2bf(x.z); o.w = f2bf(x.w);
  ((U16x4*)out)[i] = o;
}

__global__ void sfac_kernel(const float* __restrict__ omega, float* __restrict__ sfac)
{
  const int i = blockIdx.x * blockDim.x + threadIdx.x;
  if (i < D_INNER) sfac[i] = -8.f * log1pf(expf(omega[i]));  // -C*softplus(omega)
}

__global__ void vv_kernel(const u16* __restrict__ v, float* __restrict__ vinv)
{
  const int row = blockIdx.x;
  const u16* p = v + (size_t)row * D_INNER;
  float s = 0.f;
  for (int j = threadIdx.x; j < D_INNER; j += 256) {
    const float x = bf2f(p[j]);
    s += x * x;
  }
  s += __shfl_down(s, 32); s += __shfl_down(s, 16); s += __shfl_down(s, 8);
  s += __shfl_down(s, 4);  s += __shfl_down(s, 2);  s += __shfl_down(s, 1);
  __shared__ float r4[4];
  if ((threadIdx.x & 63) == 0) r4[threadIdx.x >> 6] = s;
  __syncthreads();
  if (threadIdx.x == 0) vinv[row] = 2.f / (r4[0] + r4[1] + r4[2] + r4[3]);
}

// One block per batch. 1024 threads; thread t owns channels t and t+1024.
// h_t = lam⊙(h - 2 v (v·h)/(v·v)) + (1-lam)⊙xi ; gh = silu(z)⊙h
__global__ __launch_bounds__(1024)
void scan_kernel(const u16* __restrict__ xi, const u16* __restrict__ sz,
                 const u16* __restrict__ v, const float* __restrict__ lam,
                 const float* __restrict__ vinv, u16* __restrict__ gh)
{
  const int b = blockIdx.x, tid = threadIdx.x;
  const size_t base = (size_t)b * TLEN * D_INNER;
  const int c0 = tid, c1 = tid + 1024;

  float h0 = bf2f(xi[base + c0]);
  float h1 = bf2f(xi[base + c1]);
  gh[base + c0] = f2bf(bf2f(sz[base + c0]) * h0);
  gh[base + c1] = f2bf(bf2f(sz[base + c1]) * h1);

  __shared__ float red[16];
  __shared__ float bc;

  // prefetch t=1
  size_t o1 = base + D_INNER;
  float pv0 = bf2f(v[o1 + c0]), pv1 = bf2f(v[o1 + c1]);
  float pl0 = lam[o1 + c0],     pl1 = lam[o1 + c1];
  float px0 = bf2f(xi[o1 + c0]), px1 = bf2f(xi[o1 + c1]);
  float pz0 = bf2f(sz[o1 + c0]), pz1 = bf2f(sz[o1 + c1]);
  float pvi = vinv[b * TLEN + 1];

  for (int t = 1; t < TLEN; ++t) {
    const float v0 = pv0, v1 = pv1, l0 = pl0, l1 = pl1;
    const float x0 = px0, x1 = px1, z0 = pz0, z1 = pz1, vi = pvi;
    const size_t oo = base + (size_t)t * D_INNER;
    if (t + 1 < TLEN) {  // prefetch next step; latency hides under the reduction
      const size_t on = oo + D_INNER;
      pv0 = bf2f(v[on + c0]); pv1 = bf2f(v[on + c1]);
      pl0 = lam[on + c0];     pl1 = lam[on + c1];
      px0 = bf2f(xi[on + c0]); px1 = bf2f(xi[on + c1]);
      pz0 = bf2f(sz[on + c0]); pz1 = bf2f(sz[on + c1]);
      pvi = vinv[b * TLEN + t + 1];
    }
    float part = v0 * h0 + v1 * h1;
    part += __shfl_down(part, 32);
    part += __shfl_down(part, 16);
    part += __shfl_down(part, 8);
    part += __shfl_down(part, 4);
    part += __shfl_down(part, 2);
    part += __shfl_down(part, 1);
    if ((tid & 63) == 0) red[tid >> 6] = part;
    __syncthreads();
    if (tid < 16) {
      float s = red[tid];
      s += __shfl_down(s, 8);
      s += __shfl_down(s, 4);
      s += __shfl_down(s, 2);
      s += __shfl_down(s, 1);
      if (tid == 0) bc = s;
    }
    __syncthreads();
    const float coef = bc * vi;  // 2*(v·h)/(v·v)
    h0 = l0 * (h0 - v0 * coef) + (1.f - l0) * x0;
    h1 = l1 * (h1 - v1 * coef) + (1.f - l1) * x1;
    gh[oo + c0] = f2bf(z0 * h0);
    gh[oo + c1] = f2bf(z1 * h1);
  }
}

extern "C" void kernel_launch(void* const* d_in, const int* in_sizes, int n_in,
                              void* d_out, int out_size, void* d_ws, size_t ws_size,
                              hipStream_t stream)
{
  const float* x     = (const float*)d_in[0];
  const float* omega = (const float*)d_in[1];
  const float* Win   = (const float*)d_in[2];
  const float* Wl    = (const float*)d_in[3];
  const float* bl    = (const float*)d_in[4];
  const float* Wv    = (const float*)d_in[5];
  const float* bv    = (const float*)d_in[6];
  const float* Wout  = (const float*)d_in[7];
  float* out = (float*)d_out;
  (void)in_sizes; (void)n_in; (void)out_size; (void)ws_size;

  size_t off = 0;
  auto carve = [&](size_t bytes) -> void* {
    void* r = (char*)d_ws + off;
    off += (bytes + 255) & ~(size_t)255;
    return r;
  };
  u16*  x_bf    = (u16*)carve((size_t)BT * D_MODEL * 2);          // 16.8 MB
  u16*  Win_bf  = (u16*)carve((size_t)2 * D_INNER * D_MODEL * 2); //  8.4 MB
  u16*  Wl_bf   = (u16*)carve((size_t)D_INNER * D_INNER * 2);     //  8.4 MB
  u16*  Wv_bf   = (u16*)carve((size_t)D_INNER * D_INNER * 2);     //  8.4 MB
  u16*  Wout_bf = (u16*)carve((size_t)D_MODEL * D_INNER * 2);     //  4.2 MB
  u16*  xi_bf   = (u16*)carve((size_t)BT * D_INNER * 2);          // 33.6 MB
  u16*  sz_bf   = (u16*)carve((size_t)BT * D_INNER * 2);          // 33.6 MB
  u16*  v_bf    = (u16*)carve((size_t)BT * D_INNER * 2);          // 33.6 MB
  u16*  gh_bf   = (u16*)carve((size_t)BT * D_INNER * 2);          // 33.6 MB
  float* lam    = (float*)carve((size_t)BT * D_INNER * 4);        // 67.1 MB (fp32: precision)
  float* vinv   = (float*)carve((size_t)BT * 4);
  float* sfac   = (float*)carve((size_t)D_INNER * 4);
  // total ~248 MB

  conv_bf16_kernel<<<(BT * D_MODEL / 4 + 255) / 256, 256, 0, stream>>>(x, x_bf, BT * D_MODEL / 4);
  conv_bf16_kernel<<<(2 * D_INNER * D_MODEL / 4 + 255) / 256, 256, 0, stream>>>(Win, Win_bf, 2 * D_INNER * D_MODEL / 4);
  conv_bf16_kernel<<<(D_INNER * D_INNER / 4 + 255) / 256, 256, 0, stream>>>(Wl, Wl_bf, D_INNER * D_INNER / 4);
  conv_bf16_kernel<<<(D_INNER * D_INNER / 4 + 255) / 256, 256, 0, stream>>>(Wv, Wv_bf, D_INNER * D_INNER / 4);
  conv_bf16_kernel<<<(D_MODEL * D_INNER / 4 + 255) / 256, 256, 0, stream>>>(Wout, Wout_bf, D_MODEL * D_INNER / 4);
  sfac_kernel<<<(D_INNER + 255) / 256, 256, 0, stream>>>(omega, sfac);

  // xz = x @ Win^T  -> xi (bf16) | silu(z) (bf16)
  gemm_nt<0><<<dim3(4096 / 128, BT / 128), 256, 0, stream>>>(
      x_bf, Win_bf, BT, 4096, D_MODEL, nullptr, xi_bf, sz_bf, nullptr, nullptr);
  // lam = exp(-C*softplus(omega)*sigmoid(xi@Wl^T + bl))  (fp32)
  gemm_nt<1><<<dim3(D_INNER / 128, BT / 128), 256, 0, stream>>>(
      xi_bf, Wl_bf, BT, D_INNER, D_INNER, lam, nullptr, nullptr, bl, sfac);
  // v = xi@Wv^T + bv (bf16)
  gemm_nt<2><<<dim3(D_INNER / 128, BT / 128), 256, 0, stream>>>(
      xi_bf, Wv_bf, BT, D_INNER, D_INNER, nullptr, v_bf, nullptr, bv, nullptr);
  // vinv = 2/(v·v) per (b,t)
  vv_kernel<<<BT, 256, 0, stream>>>(v_bf, vinv);
  // sequential scan -> gh = silu(z)*h (bf16)
  scan_kernel<<<NBATCH, 1024, 0, stream>>>(xi_bf, sz_bf, v_bf, lam, vinv, gh_bf);
  // out = gh @ Wout^T (fp32)
  gemm_nt<3><<<dim3(D_MODEL / 128, BT / 128), 256, 0, stream>>>(
      gh_bf, Wout_bf, BT, D_MODEL, D_INNER, out, nullptr, nullptr, nullptr, nullptr);
}

// Round 2
// 1557.235 us; speedup vs baseline: 1.3685x; 1.3685x over previous
//
#include <hip/hip_runtime.h>
#include <cstdint>
#include <cstddef>

typedef unsigned short u16;
typedef __attribute__((ext_vector_type(8))) short s8v;   // 8 bf16 in 4 VGPRs
typedef __attribute__((ext_vector_type(4))) float f4v;   // MFMA accumulator

#define D_MODEL 1024
#define D_INNER 2048
#define BT      8192   // B*T
#define TLEN    2048
#define NBATCH  4

struct alignas(8) U16x4 { u16 x, y, z, w; };

__device__ __forceinline__ u16 f2bf(float f) {
  union { float f; unsigned u; } c; c.f = f;
  unsigned r = c.u + 0x7FFFu + ((c.u >> 16) & 1u);   // RNE
  return (u16)(r >> 16);
}
__device__ __forceinline__ float bf2f(u16 b) {
  union { unsigned u; float f; } c; c.u = ((unsigned)b) << 16;
  return c.f;
}
// bf16 unpack from packed pair (u32): low ch / high ch
__device__ __forceinline__ float blo(unsigned u) {
  union { unsigned u; float f; } c; c.u = u << 16; return c.f;
}
__device__ __forceinline__ float bhi(unsigned u) {
  union { unsigned u; float f; } c; c.u = u & 0xffff0000u; return c.f;
}
// pack two fp32 -> packed bf16 pair (round half up), lo in low 16
__device__ __forceinline__ unsigned pkbf(float lo, float hi) {
  union { float f; unsigned u; } a, b; a.f = lo; b.f = hi;
#if __has_builtin(__builtin_amdgcn_perm)
  return __builtin_amdgcn_perm(b.u + 0x8000u, a.u + 0x8000u, 0x07060302u);
#else
  return ((b.u + 0x8000u) & 0xffff0000u) | ((a.u + 0x8000u) >> 16);
#endif
}

// async global->LDS, 16B per lane; LDS dest must be wave-uniform base (+lane*16 by HW)
__device__ __forceinline__ void glds16(const u16* g, const u16* lds) {
  __builtin_amdgcn_global_load_lds(
      (const __attribute__((address_space(1))) unsigned int*)(uintptr_t)g,
      (__attribute__((address_space(3))) unsigned int*)(unsigned int)(uintptr_t)lds,
      16, 0, 0);
}

// C[m,n] = sum_k A[m,k]*B[n,k]; A: MxK row-major, B: NxK row-major (both bf16).
// 256 thr = 4 waves in 2x2; each wave 64x64 = 4x4 tiles of 16x16x32 MFMA.
// EPI 0: split N=4096 -> Cb=xi bf16 (n<2048), Cb2=silu(z) bf16 (n>=2048)
// EPI 1: Cf = exp(sfac[n]*sigmoid(acc+bias[n]))  (lam, fp32)
// EPI 2: Cb = bf16(acc + bias[n])                (v)
// EPI 3: Cf = acc                                (final out)
template<int EPI>
__global__ __launch_bounds__(256, 2)
void gemm_nt(const u16* __restrict__ A, const u16* __restrict__ B,
             int M, int N, int K,
             float* __restrict__ Cf, u16* __restrict__ Cb, u16* __restrict__ Cb2,
             const float* __restrict__ bias, const float* __restrict__ sfac)
{
  __shared__ u16 lA[128 * 32];
  __shared__ u16 lB[128 * 32];
  const int tid  = threadIdx.x;
  const int wave = tid >> 6, lane = tid & 63;
  const int wm = wave >> 1, wn = wave & 1;
  const int bm0 = blockIdx.y * 128, bn0 = blockIdx.x * 128;

  const int srow = lane >> 2;
  const int scol = (lane & 3) * 8;
  const u16* pa0 = A + (size_t)(bm0 + wave * 32 + srow) * K + scol;
  const u16* pa1 = pa0 + (size_t)16 * K;
  const u16* pb0 = B + (size_t)(bn0 + wave * 32 + srow) * K + scol;
  const u16* pb1 = pb0 + (size_t)16 * K;
  u16* la0 = lA + (wave * 32) * 32;
  u16* la1 = la0 + 16 * 32;
  u16* lb0 = lB + (wave * 32) * 32;
  u16* lb1 = lb0 + 16 * 32;

  const int fr = lane & 15, kq = lane >> 4;
  const u16* fA = lA + (wm * 64 + fr) * 32 + kq * 8;
  const u16* fB = lB + (wn * 64 + fr) * 32 + kq * 8;

  f4v acc[4][4];
  const f4v zf = {0.f, 0.f, 0.f, 0.f};
  for (int i = 0; i < 4; ++i)
    for (int j = 0; j < 4; ++j)
      acc[i][j] = zf;

  for (int k0 = 0; k0 < K; k0 += 32) {
    glds16(pa0 + k0, la0);
    glds16(pa1 + k0, la1);
    glds16(pb0 + k0, lb0);
    glds16(pb1 + k0, lb1);
    __syncthreads();
    s8v af[4], bfv[4];
#pragma unroll
    for (int i = 0; i < 4; ++i) af[i] = *(const s8v*)(fA + i * 16 * 32);
#pragma unroll
    for (int j = 0; j < 4; ++j) bfv[j] = *(const s8v*)(fB + j * 16 * 32);
#pragma unroll
    for (int i = 0; i < 4; ++i)
#pragma unroll
      for (int j = 0; j < 4; ++j)
        acc[i][j] = __builtin_amdgcn_mfma_f32_16x16x32_bf16(af[i], bfv[j], acc[i][j], 0, 0, 0);
    __syncthreads();
  }

  // C/D layout: col = lane&15, row = (lane>>4)*4 + reg
#pragma unroll
  for (int i = 0; i < 4; ++i) {
#pragma unroll
    for (int j = 0; j < 4; ++j) {
#pragma unroll
      for (int r = 0; r < 4; ++r) {
        const int gm = bm0 + wm * 64 + i * 16 + kq * 4 + r;
        const int gn = bn0 + wn * 64 + j * 16 + fr;
        const float val = acc[i][j][r];
        if (EPI == 0) {
          if (gn < D_INNER) {
            Cb[(size_t)gm * D_INNER + gn] = f2bf(val);
          } else {
            const float s = val / (1.f + __expf(-val));  // silu(z)
            Cb2[(size_t)gm * D_INNER + (gn - D_INNER)] = f2bf(s);
          }
        } else if (EPI == 1) {
          const float pre = val + bias[gn];
          const float sig = 1.f / (1.f + __expf(-pre));
          Cf[(size_t)gm * N + gn] = __expf(sfac[gn] * sig);
        } else if (EPI == 2) {
          Cb[(size_t)gm * N + gn] = f2bf(val + bias[gn]);
        } else {
          Cf[(size_t)gm * N + gn] = val;
        }
      }
    }
  }
}

__global__ void conv_bf16_kernel(const float* __restrict__ in, u16* __restrict__ out, int n4)
{
  const int i = blockIdx.x * blockDim.x + threadIdx.x;
  if (i >= n4) return;
  const float4 x = ((const float4*)in)[i];
  U16x4 o; o.x = f2bf(x.x); o.y = f2bf(x.y); o.z = f2bf(x.z); o.w = f2bf(x.w);
  ((U16x4*)out)[i] = o;
}

__global__ void sfac_kernel(const float* __restrict__ omega, float* __restrict__ sfac)
{
  const int i = blockIdx.x * blockDim.x + threadIdx.x;
  if (i < D_INNER) sfac[i] = -8.f * log1pf(expf(omega[i]));  // -C*softplus(omega)
}

// v <- v * sqrt(2/(v.v)) per row; 1 wave per row, 4 rows per block, no barriers.
__global__ __launch_bounds__(256)
void vscale_kernel(u16* __restrict__ v)
{
  const int row  = blockIdx.x * 4 + (threadIdx.x >> 6);
  const int lane = threadIdx.x & 63;
  uint4* p = (uint4*)(v + (size_t)row * D_INNER + lane * 32);  // 32 ch/lane
  uint4 a[4];
#pragma unroll
  for (int i = 0; i < 4; ++i) a[i] = p[i];
  float s = 0.f;
#pragma unroll
  for (int i = 0; i < 4; ++i) {
    const unsigned w[4] = {a[i].x, a[i].y, a[i].z, a[i].w};
#pragma unroll
    for (int j = 0; j < 4; ++j) {
      const float f0 = blo(w[j]), f1 = bhi(w[j]);
      s += f0 * f0 + f1 * f1;
    }
  }
  s += __shfl_down(s, 32); s += __shfl_down(s, 16); s += __shfl_down(s, 8);
  s += __shfl_down(s, 4);  s += __shfl_down(s, 2);  s += __shfl_down(s, 1);
  const float sc = sqrtf(2.f / __shfl(s, 0));
#pragma unroll
  for (int i = 0; i < 4; ++i) {
    const unsigned w[4] = {a[i].x, a[i].y, a[i].z, a[i].w};
    unsigned o[4];
#pragma unroll
    for (int j = 0; j < 4; ++j) o[j] = pkbf(blo(w[j]) * sc, bhi(w[j]) * sc);
    uint4 ov; ov.x = o[0]; ov.y = o[1]; ov.z = o[2]; ov.w = o[3];
    p[i] = ov;
  }
}

// Sequential scan, 1 block/batch, 256 thr (4 waves), 8 ch/thread.
// v is pre-scaled: h_t = l*(h - v*(v.h) - x) + x ; gh = sz*h.
// Raw s_barrier (no vmcnt drain) + parity LDS slots + depth-3 register prefetch.
struct Step { uint4 v, x, z; float4 l0, l1; };

__global__ __launch_bounds__(256)
void scan_kernel(const u16* __restrict__ xi, const u16* __restrict__ sz,
                 const u16* __restrict__ vs, const float* __restrict__ lam,
                 u16* __restrict__ gh)
{
  const int b = blockIdx.x, tid = threadIdx.x;
  const int wave = tid >> 6, lane = tid & 63;
  const size_t base = (size_t)b * TLEN * D_INNER + (size_t)tid * 8;
  __shared__ float4 redv[2];

  auto load_step = [&](int t) {
    Step s;
    const size_t o = base + (size_t)t * D_INNER;
    s.v = *(const uint4*)(vs + o);
    s.x = *(const uint4*)(xi + o);
    s.z = *(const uint4*)(sz + o);
    const float4* lp = (const float4*)(lam + o);
    s.l0 = lp[0]; s.l1 = lp[1];
    return s;
  };

  float h[8];
  {  // t = 0: h = xi, gh = sz*h
    const uint4 x0 = *(const uint4*)(xi + base);
    const uint4 z0 = *(const uint4*)(sz + base);
    const unsigned xw[4] = {x0.x, x0.y, x0.z, x0.w};
    const unsigned zw[4] = {z0.x, z0.y, z0.z, z0.w};
    unsigned ow[4];
#pragma unroll
    for (int p = 0; p < 4; ++p) {
      h[2*p]   = blo(xw[p]);
      h[2*p+1] = bhi(xw[p]);
      ow[p] = pkbf(blo(zw[p]) * h[2*p], bhi(zw[p]) * h[2*p+1]);
    }
    uint4 out; out.x = ow[0]; out.y = ow[1]; out.z = ow[2]; out.w = ow[3];
    *(uint4*)(gh + base) = out;
  }

  Step sA = load_step(1), sB = load_step(2), sC = load_step(3);

  auto do_step = [&](Step& s, int t) {
    const int par = t & 1;
    // unpack v + per-lane partial dot (2 accumulators)
    const unsigned vw[4] = {s.v.x, s.v.y, s.v.z, s.v.w};
    float vf[8];
    float q0 = 0.f, q1 = 0.f;
#pragma unroll
    for (int p = 0; p < 4; ++p) {
      vf[2*p]   = blo(vw[p]);
      vf[2*p+1] = bhi(vw[p]);
      q0 = __builtin_fmaf(vf[2*p],   h[2*p],   q0);
      q1 = __builtin_fmaf(vf[2*p+1], h[2*p+1], q1);
    }
    float part = q0 + q1;
    // consume s into locals, then issue prefetch for t+3 early
    const uint4 xv = s.x, zv = s.z;
    const float4 la = s.l0, lb = s.l1;
    if (t + 3 < TLEN) s = load_step(t + 3);
    // wave reduce
    part += __shfl_down(part, 32);
    part += __shfl_down(part, 16);
    part += __shfl_down(part, 8);
    part += __shfl_down(part, 4);
    part += __shfl_down(part, 2);
    part += __shfl_down(part, 1);
    if (lane == 0) ((float*)&redv[par])[wave] = part;
    // order LDS write only; do NOT drain vmcnt (keeps prefetch in flight)
    asm volatile("s_waitcnt lgkmcnt(0)\n\ts_barrier" ::: "memory");
    const float4 r = redv[par];
    const float dvh = (r.x + r.y) + (r.z + r.w);   // v'.h (v' pre-scaled)
    const float lf[8] = {la.x, la.y, la.z, la.w, lb.x, lb.y, lb.z, lb.w};
    const unsigned xw[4] = {xv.x, xv.y, xv.z, xv.w};
    const unsigned zw[4] = {zv.x, zv.y, zv.z, zv.w};
    unsigned ow[4];
#pragma unroll
    for (int p = 0; p < 4; ++p) {
      const float x0 = blo(xw[p]), x1 = bhi(xw[p]);
      const float t0 = __builtin_fmaf(vf[2*p],   -dvh, h[2*p]);
      const float t1 = __builtin_fmaf(vf[2*p+1], -dvh, h[2*p+1]);
      h[2*p]   = __builtin_fmaf(lf[2*p],   t0 - x0, x0);
      h[2*p+1] = __builtin_fmaf(lf[2*p+1], t1 - x1, x1);
      ow[p] = pkbf(blo(zw[p]) * h[2*p], bhi(zw[p]) * h[2*p+1]);
    }
    uint4 out; out.x = ow[0]; out.y = ow[1]; out.z = ow[2]; out.w = ow[3];
    *(uint4*)(gh + base + (size_t)t * D_INNER) = out;
  };

  for (int t = 1; t < TLEN; t += 3) {
    do_step(sA, t);
    if (t + 1 < TLEN) do_step(sB, t + 1);
    if (t + 2 < TLEN) do_step(sC, t + 2);
  }
}

extern "C" void kernel_launch(void* const* d_in, const int* in_sizes, int n_in,
                              void* d_out, int out_size, void* d_ws, size_t ws_size,
                              hipStream_t stream)
{
  const float* x     = (const float*)d_in[0];
  const float* omega = (const float*)d_in[1];
  const float* Win   = (const float*)d_in[2];
  const float* Wl    = (const float*)d_in[3];
  const float* bl    = (const float*)d_in[4];
  const float* Wv    = (const float*)d_in[5];
  const float* bv    = (const float*)d_in[6];
  const float* Wout  = (const float*)d_in[7];
  float* out = (float*)d_out;
  (void)in_sizes; (void)n_in; (void)out_size; (void)ws_size;

  size_t off = 0;
  auto carve = [&](size_t bytes) -> void* {
    void* r = (char*)d_ws + off;
    off += (bytes + 255) & ~(size_t)255;
    return r;
  };
  u16*  x_bf    = (u16*)carve((size_t)BT * D_MODEL * 2);
  u16*  Win_bf  = (u16*)carve((size_t)2 * D_INNER * D_MODEL * 2);
  u16*  Wl_bf   = (u16*)carve((size_t)D_INNER * D_INNER * 2);
  u16*  Wv_bf   = (u16*)carve((size_t)D_INNER * D_INNER * 2);
  u16*  Wout_bf = (u16*)carve((size_t)D_MODEL * D_INNER * 2);
  u16*  xi_bf   = (u16*)carve((size_t)BT * D_INNER * 2);
  u16*  sz_bf   = (u16*)carve((size_t)BT * D_INNER * 2);
  u16*  v_bf    = (u16*)carve((size_t)BT * D_INNER * 2);
  u16*  gh_bf   = (u16*)carve((size_t)BT * D_INNER * 2);
  float* lam    = (float*)carve((size_t)BT * D_INNER * 4);   // fp32: precision
  float* sfac   = (float*)carve((size_t)D_INNER * 4);

  conv_bf16_kernel<<<(BT * D_MODEL / 4 + 255) / 256, 256, 0, stream>>>(x, x_bf, BT * D_MODEL / 4);
  conv_bf16_kernel<<<(2 * D_INNER * D_MODEL / 4 + 255) / 256, 256, 0, stream>>>(Win, Win_bf, 2 * D_INNER * D_MODEL / 4);
  conv_bf16_kernel<<<(D_INNER * D_INNER / 4 + 255) / 256, 256, 0, stream>>>(Wl, Wl_bf, D_INNER * D_INNER / 4);
  conv_bf16_kernel<<<(D_INNER * D_INNER / 4 + 255) / 256, 256, 0, stream>>>(Wv, Wv_bf, D_INNER * D_INNER / 4);
  conv_bf16_kernel<<<(D_MODEL * D_INNER / 4 + 255) / 256, 256, 0, stream>>>(Wout, Wout_bf, D_MODEL * D_INNER / 4);
  sfac_kernel<<<(D_INNER + 255) / 256, 256, 0, stream>>>(omega, sfac);

  // xz = x @ Win^T  -> xi (bf16) | silu(z) (bf16)
  gemm_nt<0><<<dim3(4096 / 128, BT / 128), 256, 0, stream>>>(
      x_bf, Win_bf, BT, 4096, D_MODEL, nullptr, xi_bf, sz_bf, nullptr, nullptr);
  // lam = exp(-C*softplus(omega)*sigmoid(xi@Wl^T + bl))  (fp32)
  gemm_nt<1><<<dim3(D_INNER / 128, BT / 128), 256, 0, stream>>>(
      xi_bf, Wl_bf, BT, D_INNER, D_INNER, lam, nullptr, nullptr, bl, sfac);
  // v = xi@Wv^T + bv (bf16)
  gemm_nt<2><<<dim3(D_INNER / 128, BT / 128), 256, 0, stream>>>(
      xi_bf, Wv_bf, BT, D_INNER, D_INNER, nullptr, v_bf, nullptr, bv, nullptr);
  // v <- v*sqrt(2/(v.v))
  vscale_kernel<<<BT / 4, 256, 0, stream>>>(v_bf);
  // sequential scan -> gh = silu(z)*h (bf16)
  scan_kernel<<<NBATCH, 256, 0, stream>>>(xi_bf, sz_bf, v_bf, lam, gh_bf);
  // out = gh @ Wout^T (fp32)
  gemm_nt<3><<<dim3(D_MODEL / 128, BT / 128), 256, 0, stream>>>(
      gh_bf, Wout_bf, BT, D_MODEL, D_INNER, out, nullptr, nullptr, nullptr, nullptr);
}

// Round 3
// 1337.854 us; speedup vs baseline: 1.5929x; 1.1640x over previous
//
#include <hip/hip_runtime.h>
#include <cstdint>
#include <cstddef>

typedef unsigned short u16;
typedef __attribute__((ext_vector_type(8))) short s8v;   // 8 bf16 in 4 VGPRs
typedef __attribute__((ext_vector_type(4))) float f4v;   // MFMA accumulator

#define D_MODEL 1024
#define D_INNER 2048
#define BT      8192   // B*T
#define TLEN    2048
#define NBATCH  4

struct alignas(8) U16x4 { u16 x, y, z, w; };

__device__ __forceinline__ u16 f2bf(float f) {
  union { float f; unsigned u; } c; c.f = f;
  unsigned r = c.u + 0x7FFFu + ((c.u >> 16) & 1u);   // RNE
  return (u16)(r >> 16);
}
__device__ __forceinline__ float bf2f(u16 b) {
  union { unsigned u; float f; } c; c.u = ((unsigned)b) << 16;
  return c.f;
}
// bf16 unpack from packed pair (u32): low ch / high ch
__device__ __forceinline__ float blo(unsigned u) {
  union { unsigned u; float f; } c; c.u = u << 16; return c.f;
}
__device__ __forceinline__ float bhi(unsigned u) {
  union { unsigned u; float f; } c; c.u = u & 0xffff0000u; return c.f;
}
// pack two fp32 -> packed bf16 pair (round half up), lo in low 16
__device__ __forceinline__ unsigned pkbf(float lo, float hi) {
  union { float f; unsigned u; } a, b; a.f = lo; b.f = hi;
#if __has_builtin(__builtin_amdgcn_perm)
  return __builtin_amdgcn_perm(b.u + 0x8000u, a.u + 0x8000u, 0x07060302u);
#else
  return ((b.u + 0x8000u) & 0xffff0000u) | ((a.u + 0x8000u) >> 16);
#endif
}

// DPP wave-64 sum: VALU-pipe latency (~5 cy/stage) instead of ds_bpermute
// (~110 cy/stage). Result valid in lane 63. gfx9-family sequence (rocPRIM).
#define DPPADD(x, ctrl) \
  ((x) + __builtin_bit_cast(float, __builtin_amdgcn_update_dpp( \
       0, __builtin_bit_cast(int, (x)), (ctrl), 0xF, 0xF, true)))
__device__ __forceinline__ float wave_sum_dpp(float x) {
  x = DPPADD(x, 0x111);  // row_shr:1
  x = DPPADD(x, 0x112);  // row_shr:2
  x = DPPADD(x, 0x114);  // row_shr:4
  x = DPPADD(x, 0x118);  // row_shr:8
  x = DPPADD(x, 0x142);  // row_bcast:15
  x = DPPADD(x, 0x143);  // row_bcast:31
  return x;              // lane 63 = wave sum
}

// async global->LDS, 16B per lane; LDS dest must be wave-uniform base (+lane*16 by HW)
__device__ __forceinline__ void glds16(const u16* g, const u16* lds) {
  __builtin_amdgcn_global_load_lds(
      (const __attribute__((address_space(1))) unsigned int*)(uintptr_t)g,
      (__attribute__((address_space(3))) unsigned int*)(unsigned int)(uintptr_t)lds,
      16, 0, 0);
}

// C[m,n] = sum_k A[m,k]*B[n,k]; A: MxK row-major, B: NxK row-major (both bf16).
// 256 thr = 4 waves in 2x2; each wave 64x64 = 4x4 tiles of 16x16x32 MFMA.
// EPI 0: split N=4096 -> Cb=xi bf16 (n<2048), Cb2=silu(z) bf16 (n>=2048)
// EPI 3: Cf = acc (final out)
// EPI 4: merged: n<2048 -> Cf = exp(sfac[n]*sigmoid(acc+bias[n])) (lam fp32)
//                n>=2048 -> Cb = bf16(acc + bias2[n-2048])        (v bf16)
template<int EPI>
__global__ __launch_bounds__(256, 2)
void gemm_nt(const u16* __restrict__ A, const u16* __restrict__ B,
             int M, int N, int K,
             float* __restrict__ Cf, u16* __restrict__ Cb, u16* __restrict__ Cb2,
             const float* __restrict__ bias, const float* __restrict__ sfac,
             const float* __restrict__ bias2)
{
  __shared__ u16 lA[128 * 32];
  __shared__ u16 lB[128 * 32];
  const int tid  = threadIdx.x;
  const int wave = tid >> 6, lane = tid & 63;
  const int wm = wave >> 1, wn = wave & 1;
  const int bm0 = blockIdx.y * 128, bn0 = blockIdx.x * 128;

  const int srow = lane >> 2;
  const int scol = (lane & 3) * 8;
  const u16* pa0 = A + (size_t)(bm0 + wave * 32 + srow) * K + scol;
  const u16* pa1 = pa0 + (size_t)16 * K;
  const u16* pb0 = B + (size_t)(bn0 + wave * 32 + srow) * K + scol;
  const u16* pb1 = pb0 + (size_t)16 * K;
  u16* la0 = lA + (wave * 32) * 32;
  u16* la1 = la0 + 16 * 32;
  u16* lb0 = lB + (wave * 32) * 32;
  u16* lb1 = lb0 + 16 * 32;

  const int fr = lane & 15, kq = lane >> 4;
  const u16* fA = lA + (wm * 64 + fr) * 32 + kq * 8;
  const u16* fB = lB + (wn * 64 + fr) * 32 + kq * 8;

  f4v acc[4][4];
  const f4v zf = {0.f, 0.f, 0.f, 0.f};
  for (int i = 0; i < 4; ++i)
    for (int j = 0; j < 4; ++j)
      acc[i][j] = zf;

  for (int k0 = 0; k0 < K; k0 += 32) {
    glds16(pa0 + k0, la0);
    glds16(pa1 + k0, la1);
    glds16(pb0 + k0, lb0);
    glds16(pb1 + k0, lb1);
    __syncthreads();
    s8v af[4], bfv[4];
#pragma unroll
    for (int i = 0; i < 4; ++i) af[i] = *(const s8v*)(fA + i * 16 * 32);
#pragma unroll
    for (int j = 0; j < 4; ++j) bfv[j] = *(const s8v*)(fB + j * 16 * 32);
#pragma unroll
    for (int i = 0; i < 4; ++i)
#pragma unroll
      for (int j = 0; j < 4; ++j)
        acc[i][j] = __builtin_amdgcn_mfma_f32_16x16x32_bf16(af[i], bfv[j], acc[i][j], 0, 0, 0);
    __syncthreads();
  }

  // C/D layout: col = lane&15, row = (lane>>4)*4 + reg
#pragma unroll
  for (int i = 0; i < 4; ++i) {
#pragma unroll
    for (int j = 0; j < 4; ++j) {
#pragma unroll
      for (int r = 0; r < 4; ++r) {
        const int gm = bm0 + wm * 64 + i * 16 + kq * 4 + r;
        const int gn = bn0 + wn * 64 + j * 16 + fr;
        const float val = acc[i][j][r];
        if (EPI == 0) {
          if (gn < D_INNER) {
            Cb[(size_t)gm * D_INNER + gn] = f2bf(val);
          } else {
            const float s = val / (1.f + __expf(-val));  // silu(z)
            Cb2[(size_t)gm * D_INNER + (gn - D_INNER)] = f2bf(s);
          }
        } else if (EPI == 4) {
          if (gn < D_INNER) {
            const float pre = val + bias[gn];
            const float sig = 1.f / (1.f + __expf(-pre));
            Cf[(size_t)gm * D_INNER + gn] = __expf(sfac[gn] * sig);
          } else {
            Cb[(size_t)gm * D_INNER + (gn - D_INNER)] = f2bf(val + bias2[gn - D_INNER]);
          }
        } else {
          Cf[(size_t)gm * N + gn] = val;
        }
      }
    }
  }
}

__global__ void conv_bf16_kernel(const float* __restrict__ in, u16* __restrict__ out, int n4)
{
  const int i = blockIdx.x * blockDim.x + threadIdx.x;
  if (i >= n4) return;
  const float4 x = ((const float4*)in)[i];
  U16x4 o; o.x = f2bf(x.x); o.y = f2bf(x.y); o.z = f2bf(x.z); o.w = f2bf(x.w);
  ((U16x4*)out)[i] = o;
}

__global__ void sfac_kernel(const float* __restrict__ omega, float* __restrict__ sfac)
{
  const int i = blockIdx.x * blockDim.x + threadIdx.x;
  if (i < D_INNER) sfac[i] = -8.f * log1pf(expf(omega[i]));  // -C*softplus(omega)
}

// v <- v * sqrt(2/(v.v)) per row; 1 wave per row, 4 rows per block.
__global__ __launch_bounds__(256)
void vscale_kernel(u16* __restrict__ v)
{
  const int row  = blockIdx.x * 4 + (threadIdx.x >> 6);
  const int lane = threadIdx.x & 63;
  uint4* p = (uint4*)(v + (size_t)row * D_INNER + lane * 32);  // 32 ch/lane
  uint4 a[4];
#pragma unroll
  for (int i = 0; i < 4; ++i) a[i] = p[i];
  float s = 0.f;
#pragma unroll
  for (int i = 0; i < 4; ++i) {
    const unsigned w[4] = {a[i].x, a[i].y, a[i].z, a[i].w};
#pragma unroll
    for (int j = 0; j < 4; ++j) {
      const float f0 = blo(w[j]), f1 = bhi(w[j]);
      s += f0 * f0 + f1 * f1;
    }
  }
  s += __shfl_down(s, 32); s += __shfl_down(s, 16); s += __shfl_down(s, 8);
  s += __shfl_down(s, 4);  s += __shfl_down(s, 2);  s += __shfl_down(s, 1);
  const float sc = sqrtf(2.f / __shfl(s, 0));
#pragma unroll
  for (int i = 0; i < 4; ++i) {
    const unsigned w[4] = {a[i].x, a[i].y, a[i].z, a[i].w};
    unsigned o[4];
#pragma unroll
    for (int j = 0; j < 4; ++j) o[j] = pkbf(blo(w[j]) * sc, bhi(w[j]) * sc);
    uint4 ov; ov.x = o[0]; ov.y = o[1]; ov.z = o[2]; ov.w = o[3];
    p[i] = ov;
  }
}

// Pair precompute (h-independent cross terms), one wave per even t:
//   w_t  = bf16(v_{t+1} ⊙ l_t)                 (row at index b*1024 + t/2)
//   C1_t = w_t · v_t        (uses ROUNDED w for exact algebra with the scan)
//   C2_t = v_{t+1} · ((1-l_t) ⊙ x_t)
__global__ __launch_bounds__(256)
void pairprep_kernel(const u16* __restrict__ vs, const float* __restrict__ lam,
                     const u16* __restrict__ xi, u16* __restrict__ w,
                     float* __restrict__ C1, float* __restrict__ C2)
{
  const int r = blockIdx.x * 4 + (threadIdx.x >> 6);  // r = b*1024 + t/2
  const int lane = threadIdx.x & 63;
  const int b = r >> 10;
  const int t = (r & 1023) * 2;
  const size_t o0 = ((size_t)b * TLEN + t) * D_INNER + (size_t)lane * 32;
  const size_t o1 = o0 + D_INNER;
  const uint4*  pv0 = (const uint4*)(vs + o0);
  const uint4*  pv1 = (const uint4*)(vs + o1);
  const uint4*  px0 = (const uint4*)(xi + o0);
  const float4* pl0 = (const float4*)(lam + o0);
  uint4* pw = (uint4*)(w + (size_t)r * D_INNER + (size_t)lane * 32);
  float c1 = 0.f, c2 = 0.f;
#pragma unroll
  for (int i = 0; i < 4; ++i) {
    const uint4 v0 = pv0[i], v1 = pv1[i], x0 = px0[i];
    const float4 la = pl0[2 * i], lb2 = pl0[2 * i + 1];
    const unsigned v0w[4] = {v0.x, v0.y, v0.z, v0.w};
    const unsigned v1w[4] = {v1.x, v1.y, v1.z, v1.w};
    const unsigned x0w[4] = {x0.x, x0.y, x0.z, x0.w};
    const float lf[8] = {la.x, la.y, la.z, la.w, lb2.x, lb2.y, lb2.z, lb2.w};
    unsigned ow[4];
#pragma unroll
    for (int q = 0; q < 4; ++q) {
      const float va = blo(v0w[q]), vb = bhi(v0w[q]);
      const float ua = blo(v1w[q]), ub = bhi(v1w[q]);
      const float xa = blo(x0w[q]), xb = bhi(x0w[q]);
      ow[q] = pkbf(ua * lf[2 * q], ub * lf[2 * q + 1]);
      c1 += blo(ow[q]) * va + bhi(ow[q]) * vb;          // rounded w
      c2 += ua * (1.f - lf[2 * q]) * xa + ub * (1.f - lf[2 * q + 1]) * xb;
    }
    uint4 o; o.x = ow[0]; o.y = ow[1]; o.z = ow[2]; o.w = ow[3];
    pw[i] = o;
  }
  c1 = wave_sum_dpp(c1);
  c2 = wave_sum_dpp(c2);
  if (lane == 63) { C1[r] = c1; C2[r] = c2; }
}

// Paired sequential scan: 1 block/batch, 256 thr (4 waves), 8 ch/thread.
// Per pair (t,t+1): both dots from h_{t-1} (P = v_t·h, Q = w_t·h), joint DPP
// reduce, ONE LDS round-trip + raw s_barrier (no vmcnt drain), then
//   a_t = ΣP ; a_{t+1} = ΣQ − a_t·C1_t + C2_t
// and two elementwise h-updates. v is pre-scaled (h -= v·(v·h)).
struct Pair {
  uint4 v0, v1, w, x0, x1, z0, z1;
  float4 l0a, l0b, l1a, l1b;
  float c1, c2;
};

__global__ __launch_bounds__(256, 1)
void scan2_kernel(const u16* __restrict__ xi, const u16* __restrict__ sz,
                  const u16* __restrict__ vs, const float* __restrict__ lam,
                  const u16* __restrict__ whalf, const float* __restrict__ C1,
                  const float* __restrict__ C2, u16* __restrict__ gh)
{
  const int b = blockIdx.x, tid = threadIdx.x;
  const int wave = tid >> 6, lane = tid & 63;
  const size_t base = (size_t)b * TLEN * D_INNER + (size_t)tid * 8;
  const size_t wb0  = (size_t)(b * 1024) * D_INNER + (size_t)tid * 8;
  const int cb0 = b * 1024;
  __shared__ __attribute__((aligned(16))) float rP[2][4], rQ[2][4];

  auto load_pair = [&](int t) {
    Pair p;
    const size_t o0 = base + (size_t)t * D_INNER;
    const size_t o1 = o0 + D_INNER;
    p.v0 = *(const uint4*)(vs + o0);
    p.v1 = *(const uint4*)(vs + o1);
    p.w  = *(const uint4*)(whalf + wb0 + (size_t)(t >> 1) * D_INNER);
    p.x0 = *(const uint4*)(xi + o0);
    p.x1 = *(const uint4*)(xi + o1);
    p.z0 = *(const uint4*)(sz + o0);
    p.z1 = *(const uint4*)(sz + o1);
    const float4* l0p = (const float4*)(lam + o0);
    p.l0a = l0p[0]; p.l0b = l0p[1];
    const float4* l1p = (const float4*)(lam + o1);
    p.l1a = l1p[0]; p.l1b = l1p[1];
    const int ci = cb0 + (t >> 1);
    p.c1 = C1[ci]; p.c2 = C2[ci];
    return p;
  };

  float h[8];
  {  // t = 0: h = xi, gh = sz*h
    const uint4 x0 = *(const uint4*)(xi + base);
    const uint4 z0 = *(const uint4*)(sz + base);
    const unsigned xw[4] = {x0.x, x0.y, x0.z, x0.w};
    const unsigned zw[4] = {z0.x, z0.y, z0.z, z0.w};
    unsigned ow[4];
#pragma unroll
    for (int p = 0; p < 4; ++p) {
      h[2*p]   = blo(xw[p]);
      h[2*p+1] = bhi(xw[p]);
      ow[p] = pkbf(blo(zw[p]) * h[2*p], bhi(zw[p]) * h[2*p+1]);
    }
    uint4 out; out.x = ow[0]; out.y = ow[1]; out.z = ow[2]; out.w = ow[3];
    *(uint4*)(gh + base) = out;
  }

  Pair pA = load_pair(2);
  Pair pB = load_pair(4);

  {  // solo step t = 1
    const size_t o = base + D_INNER;
    const uint4 v1v = *(const uint4*)(vs + o);
    const uint4 x1v = *(const uint4*)(xi + o);
    const uint4 z1v = *(const uint4*)(sz + o);
    const float4* lp = (const float4*)(lam + o);
    const float4 la = lp[0], lb2 = lp[1];
    const unsigned vw[4] = {v1v.x, v1v.y, v1v.z, v1v.w};
    float vf[8];
    float P0 = 0.f, P1 = 0.f;
#pragma unroll
    for (int p = 0; p < 4; ++p) {
      vf[2*p]   = blo(vw[p]);
      vf[2*p+1] = bhi(vw[p]);
      P0 = __builtin_fmaf(vf[2*p],   h[2*p],   P0);
      P1 = __builtin_fmaf(vf[2*p+1], h[2*p+1], P1);
    }
    float P = wave_sum_dpp(P0 + P1);
    if (lane == 63) rP[0][wave] = P;
    asm volatile("s_waitcnt lgkmcnt(0)\n\ts_barrier" ::: "memory");
    const float4 sp = *(const float4*)rP[0];
    const float a = (sp.x + sp.y) + (sp.z + sp.w);
    const float lf[8] = {la.x, la.y, la.z, la.w, lb2.x, lb2.y, lb2.z, lb2.w};
    const unsigned xw[4] = {x1v.x, x1v.y, x1v.z, x1v.w};
    const unsigned zw[4] = {z1v.x, z1v.y, z1v.z, z1v.w};
    unsigned ow[4];
#pragma unroll
    for (int p = 0; p < 4; ++p) {
      const float X0 = blo(xw[p]), X1 = bhi(xw[p]);
      const float t0 = __builtin_fmaf(vf[2*p],   -a, h[2*p]);
      const float t1 = __builtin_fmaf(vf[2*p+1], -a, h[2*p+1]);
      h[2*p]   = __builtin_fmaf(lf[2*p],   t0 - X0, X0);
      h[2*p+1] = __builtin_fmaf(lf[2*p+1], t1 - X1, X1);
      ow[p] = pkbf(blo(zw[p]) * h[2*p], bhi(zw[p]) * h[2*p+1]);
    }
    uint4 out; out.x = ow[0]; out.y = ow[1]; out.z = ow[2]; out.w = ow[3];
    *(uint4*)(gh + o) = out;
  }

  auto do_pair = [&](Pair& p, int t) {
    const int par = (t >> 1) & 1;
    const unsigned vw[4] = {p.v0.x, p.v0.y, p.v0.z, p.v0.w};
    const unsigned ww[4] = {p.w.x, p.w.y, p.w.z, p.w.w};
    float vf[8];
    float P0 = 0.f, P1 = 0.f, Q0 = 0.f, Q1 = 0.f;
#pragma unroll
    for (int q = 0; q < 4; ++q) {
      vf[2*q]   = blo(vw[q]);
      vf[2*q+1] = bhi(vw[q]);
      const float wa = blo(ww[q]), wb = bhi(ww[q]);
      P0 = __builtin_fmaf(vf[2*q],   h[2*q],   P0);
      P1 = __builtin_fmaf(vf[2*q+1], h[2*q+1], P1);
      Q0 = __builtin_fmaf(wa, h[2*q],   Q0);
      Q1 = __builtin_fmaf(wb, h[2*q+1], Q1);
    }
    float P = P0 + P1, Q = Q0 + Q1;
    // snapshot operands, then prefetch pair t+4 (stays in flight: no vmcnt drain)
    const uint4 v1v = p.v1, x0v = p.x0, x1v = p.x1, z0v = p.z0, z1v = p.z1;
    const float lf0[8] = {p.l0a.x, p.l0a.y, p.l0a.z, p.l0a.w,
                          p.l0b.x, p.l0b.y, p.l0b.z, p.l0b.w};
    const float lf1[8] = {p.l1a.x, p.l1a.y, p.l1a.z, p.l1a.w,
                          p.l1b.x, p.l1b.y, p.l1b.z, p.l1b.w};
    const float c1 = p.c1, c2 = p.c2;
    if (t + 4 <= 2046) p = load_pair(t + 4);
    P = wave_sum_dpp(P);
    Q = wave_sum_dpp(Q);
    if (lane == 63) { rP[par][wave] = P; rQ[par][wave] = Q; }
    asm volatile("s_waitcnt lgkmcnt(0)\n\ts_barrier" ::: "memory");
    const float4 sp = *(const float4*)rP[par];
    const float4 sq = *(const float4*)rQ[par];
    const float a0 = (sp.x + sp.y) + (sp.z + sp.w);
    const float a1 = __builtin_fmaf(-a0, c1, (sq.x + sq.y) + (sq.z + sq.w) + c2);
    const unsigned v1w[4] = {v1v.x, v1v.y, v1v.z, v1v.w};
    const unsigned xw0[4] = {x0v.x, x0v.y, x0v.z, x0v.w};
    const unsigned xw1[4] = {x1v.x, x1v.y, x1v.z, x1v.w};
    const unsigned zw0[4] = {z0v.x, z0v.y, z0v.z, z0v.w};
    const unsigned zw1[4] = {z1v.x, z1v.y, z1v.z, z1v.w};
    unsigned ow0[4], ow1[4];
#pragma unroll
    for (int q = 0; q < 4; ++q) {
      const float A0 = blo(xw0[q]), A1 = bhi(xw0[q]);
      const float B0 = blo(xw1[q]), B1 = bhi(xw1[q]);
      float t0 = __builtin_fmaf(vf[2*q],   -a0, h[2*q]);
      float t1 = __builtin_fmaf(vf[2*q+1], -a0, h[2*q+1]);
      t0 = __builtin_fmaf(lf0[2*q],   t0 - A0, A0);   // h_t
      t1 = __builtin_fmaf(lf0[2*q+1], t1 - A1, A1);
      ow0[q] = pkbf(blo(zw0[q]) * t0, bhi(zw0[q]) * t1);
      const float u0 = __builtin_fmaf(blo(v1w[q]), -a1, t0);
      const float u1 = __builtin_fmaf(bhi(v1w[q]), -a1, t1);
      h[2*q]   = __builtin_fmaf(lf1[2*q],   u0 - B0, B0);   // h_{t+1}
      h[2*q+1] = __builtin_fmaf(lf1[2*q+1], u1 - B1, B1);
      ow1[q] = pkbf(blo(zw1[q]) * h[2*q], bhi(zw1[q]) * h[2*q+1]);
    }
    const size_t oo = base + (size_t)t * D_INNER;
    uint4 o0; o0.x = ow0[0]; o0.y = ow0[1]; o0.z = ow0[2]; o0.w = ow0[3];
    uint4 o1; o1.x = ow1[0]; o1.y = ow1[1]; o1.z = ow1[2]; o1.w = ow1[3];
    *(uint4*)(gh + oo) = o0;
    *(uint4*)(gh + oo + D_INNER) = o1;
  };

  for (int t = 2; t <= 2046; t += 4) {
    do_pair(pA, t);
    if (t + 2 <= 2046) do_pair(pB, t + 2);
  }
}

extern "C" void kernel_launch(void* const* d_in, const int* in_sizes, int n_in,
                              void* d_out, int out_size, void* d_ws, size_t ws_size,
                              hipStream_t stream)
{
  const float* x     = (const float*)d_in[0];
  const float* omega = (const float*)d_in[1];
  const float* Win   = (const float*)d_in[2];
  const float* Wl    = (const float*)d_in[3];
  const float* bl    = (const float*)d_in[4];
  const float* Wv    = (const float*)d_in[5];
  const float* bv    = (const float*)d_in[6];
  const float* Wout  = (const float*)d_in[7];
  float* out = (float*)d_out;
  (void)in_sizes; (void)n_in; (void)out_size; (void)ws_size;

  size_t off = 0;
  auto carve = [&](size_t bytes) -> void* {
    void* r = (char*)d_ws + off;
    off += (bytes + 255) & ~(size_t)255;
    return r;
  };
  u16*  x_bf    = (u16*)carve((size_t)BT * D_MODEL * 2);          // dead after gemm<0>
  u16*  Win_bf  = (u16*)carve((size_t)2 * D_INNER * D_MODEL * 2);
  u16*  Wl_bf   = (u16*)carve((size_t)D_INNER * D_INNER * 2);     // [Wl; Wv] contiguous
  u16*  Wv_bf   = (u16*)carve((size_t)D_INNER * D_INNER * 2);
  u16*  Wout_bf = (u16*)carve((size_t)D_MODEL * D_INNER * 2);
  u16*  xi_bf   = (u16*)carve((size_t)BT * D_INNER * 2);
  u16*  sz_bf   = (u16*)carve((size_t)BT * D_INNER * 2);
  u16*  v_bf    = (u16*)carve((size_t)BT * D_INNER * 2);
  u16*  gh_bf   = (u16*)carve((size_t)BT * D_INNER * 2);
  float* lam    = (float*)carve((size_t)BT * D_INNER * 4);        // fp32: precision
  float* sfac   = (float*)carve((size_t)D_INNER * 4);
  float* C1     = (float*)carve((size_t)(BT / 2) * 4);
  float* C2     = (float*)carve((size_t)(BT / 2) * 4);
  u16*  whalf   = x_bf;  // reuse: same size (BT/2*D_INNER*2 == BT*D_MODEL*2)

  conv_bf16_kernel<<<(BT * D_MODEL / 4 + 255) / 256, 256, 0, stream>>>(x, x_bf, BT * D_MODEL / 4);
  conv_bf16_kernel<<<(2 * D_INNER * D_MODEL / 4 + 255) / 256, 256, 0, stream>>>(Win, Win_bf, 2 * D_INNER * D_MODEL / 4);
  conv_bf16_kernel<<<(D_INNER * D_INNER / 4 + 255) / 256, 256, 0, stream>>>(Wl, Wl_bf, D_INNER * D_INNER / 4);
  conv_bf16_kernel<<<(D_INNER * D_INNER / 4 + 255) / 256, 256, 0, stream>>>(Wv, Wv_bf, D_INNER * D_INNER / 4);
  conv_bf16_kernel<<<(D_MODEL * D_INNER / 4 + 255) / 256, 256, 0, stream>>>(Wout, Wout_bf, D_MODEL * D_INNER / 4);
  sfac_kernel<<<(D_INNER + 255) / 256, 256, 0, stream>>>(omega, sfac);

  // xz = x @ Win^T  -> xi (bf16) | silu(z) (bf16)
  gemm_nt<0><<<dim3(4096 / 128, BT / 128), 256, 0, stream>>>(
      x_bf, Win_bf, BT, 4096, D_MODEL, nullptr, xi_bf, sz_bf, nullptr, nullptr, nullptr);
  // merged: lam = exp(sfac*sigmoid(xi@Wl^T+bl)) fp32 | v = xi@Wv^T+bv bf16
  gemm_nt<4><<<dim3(4096 / 128, BT / 128), 256, 0, stream>>>(
      xi_bf, Wl_bf, BT, 4096, D_INNER, lam, v_bf, nullptr, bl, sfac, bv);
  // v <- v*sqrt(2/(v.v))
  vscale_kernel<<<BT / 4, 256, 0, stream>>>(v_bf);
  // pair cross-terms: w = v_{t+1}*l_t (bf16), C1, C2
  pairprep_kernel<<<BT / 2 / 4, 256, 0, stream>>>(v_bf, lam, xi_bf, whalf, C1, C2);
  // paired sequential scan -> gh = silu(z)*h (bf16)
  scan2_kernel<<<NBATCH, 256, 0, stream>>>(xi_bf, sz_bf, v_bf, lam, whalf, C1, C2, gh_bf);
  // out = gh @ Wout^T (fp32)
  gemm_nt<3><<<dim3(D_MODEL / 128, BT / 128), 256, 0, stream>>>(
      gh_bf, Wout_bf, BT, D_MODEL, D_INNER, out, nullptr, nullptr, nullptr, nullptr, nullptr);
}